// Round 7
// baseline (48.763 us; speedup 1.0000x reference)
//
#include <hip/hip_runtime.h>

// PSRoIPool: features (B=2, C=1029, H=100, W=100) f32, rois (R=512, 5) f32.
// Output: (R, D=21, P=7, P=7) f32.
// out[r,d,ph,pw] = mean over features[b, (d*7+ph)*7+pw, hs:he, ws:we], 0 if empty.
//
// History: absmax bit-identical (0.6044921875) for 6 variants spanning
// {fma,no-fma}x{f32,f64} bounds and {direct-f32, direct-f64, integral-f32}
// sums => argmax element has a SHIFTED WINDOW in the reference, caused by a
// bound perturbation none of those variants had. Hypothesis: XLA CPU
// fast-math rewrites roi_w/7 as roi_w * float(1/7) (arcp), 1 ulp off the
// true divide => knife-edge floor/ceil flip. This round: reciprocal-multiply
// bins + fmaf bounds (XLA also fuses mul+add). Window values keep the
// accurate direct sum (value noise << 0.073 threshold; only placement matters).

#define POOLED 7
#define GROUP 7
#define OUT_DIM 21
#define FH 100
#define FW 100
#define NCH (OUT_DIM * GROUP * GROUP)  // 1029
#define PER_ROI (OUT_DIM * POOLED * POOLED)  // 1029

__device__ __forceinline__ float fbar(float x) { asm volatile("" : "+v"(x)); return x; }

__global__ __launch_bounds__(256) void psroi_kernel(
    const float* __restrict__ feat,
    const float* __restrict__ rois,
    float* __restrict__ out,
    int R)
{
    int idx = blockIdx.x * blockDim.x + threadIdx.x;
    int total = R * PER_ROI;
    if (idx >= total) return;

    int r    = idx / PER_ROI;
    int rem  = idx - r * PER_ROI;
    int d    = rem / (POOLED * POOLED);
    int rem2 = rem - d * (POOLED * POOLED);
    int ph   = rem2 / POOLED;
    int pw   = rem2 - ph * POOLED;

    const float* roi = rois + (size_t)r * 5;
    int b = (int)roi[0];

    // All corner values are exact f32 (multiples of 2^-4, < 128):
    const float scale = 0.0625f;
    float sw = rintf(roi[1]) * scale;
    float sh = rintf(roi[2]) * scale;
    float ew = (rintf(roi[3]) + 1.0f) * scale;
    float eh = (rintf(roi[4]) + 1.0f) * scale;
    float roi_w = fmaxf(ew - sw, 0.1f);   // exact subtraction
    float roi_h = fmaxf(eh - sh, 0.1f);

    // XLA CPU fast-math (arcp): x/7 -> x * float(1/7). Emulate exactly:
    const float rcp7 = 1.0f / 7.0f;       // compile-time, correctly rounded
    float bin_w = fbar(roi_w * rcp7);     // single f32 mul rounding
    float bin_h = fbar(roi_h * rcp7);

    float phf = (float)ph;
    float pwf = (float)pw;
    // XLA fuses mul+add -> fma; match with explicit fmaf:
    float th0 = __builtin_fmaf(phf,        bin_h, sh);
    float th1 = __builtin_fmaf(phf + 1.0f, bin_h, sh);
    float tw0 = __builtin_fmaf(pwf,        bin_w, sw);
    float tw1 = __builtin_fmaf(pwf + 1.0f, bin_w, sw);

    int hs = (int)fminf(fmaxf(floorf(th0), 0.0f), (float)FH);
    int he = (int)fminf(fmaxf(ceilf(th1),  0.0f), (float)FH);
    int ws = (int)fminf(fmaxf(floorf(tw0), 0.0f), (float)FW);
    int we = (int)fminf(fmaxf(ceilf(tw1),  0.0f), (float)FW);

    int ch = (d * GROUP + ph) * GROUP + pw;
    const float* f = feat + ((size_t)b * NCH + ch) * (FH * FW);

    int area = (he - hs) * (we - ws);
    float s = 0.0f;
    for (int h = hs; h < he; ++h) {
        const float* row = f + h * FW;
        for (int w = ws; w < we; ++w) s += row[w];
    }
    out[idx] = (area > 0) ? s / (float)area : 0.0f;
}

extern "C" void kernel_launch(void* const* d_in, const int* in_sizes, int n_in,
                              void* d_out, int out_size, void* d_ws, size_t ws_size,
                              hipStream_t stream) {
    const float* feat = (const float*)d_in[0];
    const float* rois = (const float*)d_in[1];
    float* out = (float*)d_out;
    int R = in_sizes[1] / 5;  // 512
    int total = R * PER_ROI;
    int block = 256;
    int grid = (total + block - 1) / block;
    psroi_kernel<<<grid, block, 0, stream>>>(feat, rois, out, R);
}

// Round 8
// 34.961 us; speedup vs baseline: 1.3948x; 1.3948x over previous
//
#include <hip/hip_runtime.h>

// PSRoIPool: features (B=2, C=1029, H=100, W=100) f32, rois (R=512, 5) f32.
// Output: (R, D=21, P=7, P=7) f32;  out[r*1029 + ch], ch=(d*7+ph)*7+pw.
//
// Correctness-critical (round 7): window bounds must match XLA-CPU fast-math:
// bin = roi * float(1/7) (reciprocal multiply, NOT true divide), then
// fmaf(p, bin, s). Changing either re-breaks the knife-edge ROI (absmax 0.6).
//
// Perf structure (round 8): block per channel; stage both batch planes
// (2 x 40KB) in LDS via coalesced float4 streaming, then per-ROI window sums
// from LDS. Converts a 64-planes-per-wave scatter (138MB fetch, L1 thrash,
// 34% HBM) into one clean pass over the 82MB feature map.

#define POOLED 7
#define GROUP 7
#define OUT_DIM 21
#define FH 100
#define FW 100
#define NCH (OUT_DIM * GROUP * GROUP)  // 1029
#define PLANE (FH * FW)                // 10000
#define PER_ROI NCH

__device__ __forceinline__ float fbar(float x) { asm volatile("" : "+v"(x)); return x; }

__global__ __launch_bounds__(256) void psroi_chan_kernel(
    const float* __restrict__ feat,
    const float* __restrict__ rois,
    float* __restrict__ out,
    int R)
{
    __shared__ float lds[2 * PLANE];     // 80 KB: plane for b=0 and b=1
    const int ch  = blockIdx.x;          // 0..1028
    const int tid = threadIdx.x;

    // ---- stage both batch planes, coalesced float4 ----
    const float4* s0 = (const float4*)(feat + (size_t)ch * PLANE);          // b=0
    const float4* s1 = (const float4*)(feat + ((size_t)NCH + ch) * PLANE);  // b=1
    float4* l0 = (float4*)lds;
    float4* l1 = (float4*)(lds + PLANE);
    #pragma unroll
    for (int i = tid; i < PLANE / 4; i += 256) l0[i] = s0[i];
    #pragma unroll
    for (int i = tid; i < PLANE / 4; i += 256) l1[i] = s1[i];
    __syncthreads();

    const int pw = ch % GROUP;
    const int ph = (ch / GROUP) % GROUP;
    // d = ch / 49 — not needed beyond ch itself.

    const float rcp7 = 1.0f / 7.0f;
    const float scale = 0.0625f;
    const float phf = (float)ph;
    const float pwf = (float)pw;

    for (int r = tid; r < R; r += 256) {
        const float* roi = rois + (size_t)r * 5;
        int b = (int)roi[0];

        // exact f32 (multiples of 2^-4 < 128):
        float sw = rintf(roi[1]) * scale;
        float sh = rintf(roi[2]) * scale;
        float ew = (rintf(roi[3]) + 1.0f) * scale;
        float eh = (rintf(roi[4]) + 1.0f) * scale;
        float roi_w = fmaxf(ew - sw, 0.1f);
        float roi_h = fmaxf(eh - sh, 0.1f);

        // XLA-CPU fast-math semantics: reciprocal multiply + fused mul-add
        float bin_w = fbar(roi_w * rcp7);
        float bin_h = fbar(roi_h * rcp7);
        float th0 = __builtin_fmaf(phf,        bin_h, sh);
        float th1 = __builtin_fmaf(phf + 1.0f, bin_h, sh);
        float tw0 = __builtin_fmaf(pwf,        bin_w, sw);
        float tw1 = __builtin_fmaf(pwf + 1.0f, bin_w, sw);

        int hs = (int)fminf(fmaxf(floorf(th0), 0.0f), (float)FH);
        int he = (int)fminf(fmaxf(ceilf(th1),  0.0f), (float)FH);
        int ws = (int)fminf(fmaxf(floorf(tw0), 0.0f), (float)FW);
        int we = (int)fminf(fmaxf(ceilf(tw1),  0.0f), (float)FW);

        const float* p = lds + b * PLANE;
        int area = (he - hs) * (we - ws);
        float s = 0.0f;
        for (int h = hs; h < he; ++h) {
            const float* row = p + h * FW;
            for (int w = ws; w < we; ++w) s += row[w];
        }
        out[(size_t)r * PER_ROI + ch] = (area > 0) ? s / (float)area : 0.0f;
    }
}

extern "C" void kernel_launch(void* const* d_in, const int* in_sizes, int n_in,
                              void* d_out, int out_size, void* d_ws, size_t ws_size,
                              hipStream_t stream) {
    const float* feat = (const float*)d_in[0];
    const float* rois = (const float*)d_in[1];
    float* out = (float*)d_out;
    int R = in_sizes[1] / 5;  // 512
    psroi_chan_kernel<<<NCH, 256, 0, stream>>>(feat, rois, out, R);
}

// Round 9
// 32.368 us; speedup vs baseline: 1.5065x; 1.0801x over previous
//
#include <hip/hip_runtime.h>

// PSRoIPool: features (B=2, C=1029, H=100, W=100) f32, rois (R=512, 5) f32.
// Output: (R, D=21, P=7, P=7) f32;  out[r*1029 + ch], ch=(d*7+ph)*7+pw.
//
// Correctness-critical (round 7): window bounds must match XLA-CPU fast-math:
// bin = roi * float(1/7) (reciprocal multiply, NOT true divide), then
// fmaf(p, bin, s). Changing either re-breaks the knife-edge ROI (absmax 0.6).
//
// Perf (round 9): block-per-channel DIRECT gather (no LDS). Round 8's 80KB
// LDS staging capped occupancy at 2 blocks/CU (14.6%) and staged 100% of
// every plane to use ~30%; the kernel was latency-bound (VALU 4.5%, HBM 10%).
// All lanes of a wave share one channel's two planes -> L1/L2-resident gather;
// no barrier, no LDS -> occupancy limited only by VGPRs.

#define POOLED 7
#define GROUP 7
#define OUT_DIM 21
#define FH 100
#define FW 100
#define NCH (OUT_DIM * GROUP * GROUP)  // 1029
#define PLANE (FH * FW)                // 10000
#define PER_ROI NCH

__device__ __forceinline__ float fbar(float x) { asm volatile("" : "+v"(x)); return x; }

__global__ __launch_bounds__(256) void psroi_direct_kernel(
    const float* __restrict__ feat,
    const float* __restrict__ rois,
    float* __restrict__ out,
    int R)
{
    const int ch  = blockIdx.x;          // 0..1028
    const int tid = threadIdx.x;

    const int pw = ch % GROUP;
    const int ph = (ch / GROUP) % GROUP;

    const float rcp7 = 1.0f / 7.0f;
    const float scale = 0.0625f;
    const float phf = (float)ph;
    const float pwf = (float)pw;

    const float* p0 = feat + (size_t)ch * PLANE;           // b=0 plane
    const float* p1 = feat + ((size_t)NCH + ch) * PLANE;   // b=1 plane

    for (int r = tid; r < R; r += 256) {
        const float* roi = rois + (size_t)r * 5;
        int b = (int)roi[0];

        // exact f32 (multiples of 2^-4 < 128):
        float sw = rintf(roi[1]) * scale;
        float sh = rintf(roi[2]) * scale;
        float ew = (rintf(roi[3]) + 1.0f) * scale;
        float eh = (rintf(roi[4]) + 1.0f) * scale;
        float roi_w = fmaxf(ew - sw, 0.1f);
        float roi_h = fmaxf(eh - sh, 0.1f);

        // XLA-CPU fast-math semantics: reciprocal multiply + fused mul-add
        float bin_w = fbar(roi_w * rcp7);
        float bin_h = fbar(roi_h * rcp7);
        float th0 = __builtin_fmaf(phf,        bin_h, sh);
        float th1 = __builtin_fmaf(phf + 1.0f, bin_h, sh);
        float tw0 = __builtin_fmaf(pwf,        bin_w, sw);
        float tw1 = __builtin_fmaf(pwf + 1.0f, bin_w, sw);

        int hs = (int)fminf(fmaxf(floorf(th0), 0.0f), (float)FH);
        int he = (int)fminf(fmaxf(ceilf(th1),  0.0f), (float)FH);
        int ws = (int)fminf(fmaxf(floorf(tw0), 0.0f), (float)FW);
        int we = (int)fminf(fmaxf(ceilf(tw1),  0.0f), (float)FW);

        const float* p = b ? p1 : p0;
        int area = (he - hs) * (we - ws);
        float s = 0.0f;
        for (int h = hs; h < he; ++h) {
            const float* row = p + h * FW;
            for (int w = ws; w < we; ++w) s += row[w];
        }
        out[(size_t)r * PER_ROI + ch] = (area > 0) ? s / (float)area : 0.0f;
    }
}

extern "C" void kernel_launch(void* const* d_in, const int* in_sizes, int n_in,
                              void* d_out, int out_size, void* d_ws, size_t ws_size,
                              hipStream_t stream) {
    const float* feat = (const float*)d_in[0];
    const float* rois = (const float*)d_in[1];
    float* out = (float*)d_out;
    int R = in_sizes[1] / 5;  // 512
    psroi_direct_kernel<<<NCH, 256, 0, stream>>>(feat, rois, out, R);
}